// Round 1
// baseline (462.408 us; speedup 1.0000x reference)
//
#include <hip/hip_runtime.h>
#include <hip/hip_bf16.h>

// Problem constants (GATLayer): B=8, C=2048, IN=OUT=128, H=4, D=32
constexpr int B_  = 8;
constexpr int C_  = 2048;
constexpr int IND = 128;
constexpr int H_  = 4;
constexpr int D_  = 32;
constexpr int M_  = B_ * C_;          // 16384 tokens
constexpr float QSCALE = 0.17677669529663687f;   // 1/sqrt(32)
constexpr float L2E    = 1.4426950408889634f;
constexpr float QL2    = QSCALE * L2E;           // folded into Wt Q-rows

constexpr int KSPLIT = 4;             // global split (Opart = 33.6 MB, ws fits)
constexpr int KPG = C_ / KSPLIT;      // 512 keys per (block, kz)

typedef __attribute__((ext_vector_type(8))) short short8;
typedef __attribute__((ext_vector_type(4))) short s4t;
typedef __attribute__((ext_vector_type(4))) float f4t;
typedef __attribute__((ext_vector_type(4))) unsigned short us4;

// Device pass has these; host pass doesn't advertise via __has_builtin.
#if __has_builtin(__builtin_amdgcn_mfma_f32_16x16x16bf16_1k)
#define MFMA16(a, b, c) __builtin_amdgcn_mfma_f32_16x16x16bf16_1k(a, b, c, 0, 0, 0)
#else
#define MFMA16(a, b, c) (c)   // host-pass placeholder
#endif
#define MFMA32(a, b, c) __builtin_amdgcn_mfma_f32_16x16x32_bf16(a, b, c, 0, 0, 0)

__device__ __forceinline__ unsigned short f2bf(float f) {
    union { float f; unsigned u; } v; v.f = f;
    unsigned u = v.u + 0x7fffu + ((v.u >> 16) & 1u);   // RNE
    return (unsigned short)(u >> 16);
}

__device__ __forceinline__ s4t pack4_bf16(float p0, float p1, float p2, float p3) {
#if __has_builtin(__builtin_amdgcn_cvt_pk_bf16_f32)
    auto a = __builtin_amdgcn_cvt_pk_bf16_f32(p0, p1);
    auto b = __builtin_amdgcn_cvt_pk_bf16_f32(p2, p3);
    unsigned u[2];
    __builtin_memcpy(&u[0], &a, 4);
    __builtin_memcpy(&u[1], &b, 4);
    s4t pp;
    __builtin_memcpy(&pp, u, 8);
    return pp;
#else
    s4t pp;
    pp[0] = (short)f2bf(p0); pp[1] = (short)f2bf(p1);
    pp[2] = (short)f2bf(p2); pp[3] = (short)f2bf(p3);
    return pp;
#endif
}

__device__ __forceinline__ short8 cvt8(float4 a, float4 b) {
    s4t x = pack4_bf16(a.x, a.y, a.z, a.w);
    s4t y = pack4_bf16(b.x, b.y, b.z, b.w);
    short8 r;
    r[0] = x[0]; r[1] = x[1]; r[2] = x[2]; r[3] = x[3];
    r[4] = y[0]; r[5] = y[1]; r[6] = y[2]; r[7] = y[3];
    return r;
}

// ---------------------------------------------------------------------------
// K0: weight prep. Wtb[512][128] bf16: row n = column n of the fused weight
// [Wq*QL2 | Wk | Wv | Wo].  LDS tile transpose, padded stride.
__global__ __launch_bounds__(256) void prep_w_kernel(
    const float* __restrict__ Wq, const float* __restrict__ Wk,
    const float* __restrict__ Wv, const float* __restrict__ Wo,
    unsigned short* __restrict__ Wtb)
{
    __shared__ unsigned short lds[16][130];
    const int t  = threadIdx.x;
    const int n0 = blockIdx.x * 16;          // 0..511 in steps of 16

    const float* src; int nb; float sc = 1.0f;
    if      (n0 < 128) { src = Wq; nb = n0;       sc = QL2; }
    else if (n0 < 256) { src = Wk; nb = n0 - 128; }
    else if (n0 < 384) { src = Wv; nb = n0 - 256; }
    else               { src = Wo; nb = n0 - 384; }

    const int nn = t & 15, kk = t >> 4;      // kk: 0..15
#pragma unroll
    for (int kb = 0; kb < 8; ++kb) {
        const int k = kb * 16 + kk;
        lds[nn][k] = f2bf(src[k * IND + nb + nn] * sc);
    }
    __syncthreads();
    const int k = t & 127, rr = t >> 7;      // rr: 0..1
#pragma unroll
    for (int it = 0; it < 8; ++it) {
        const int r = it * 2 + rr;
        Wtb[(size_t)(n0 + r) * IND + k] = lds[r][k];
    }
}

// ---------------------------------------------------------------------------
// K1: QKV projection via MFMA. Block = 192 = 3 waves (one per matrix);
// grid (M/16, 2): grid.y splits the 8 N-tiles into two halves -> 6144 waves.
// Q/K computed TRANSPOSED (coalesced 8B row stores); V computed normal ->
// lands directly in Vt[b][d][c] layout.
__global__ __launch_bounds__(192) void qkv_proj_kernel(
    const float* __restrict__ x, const unsigned short* __restrict__ Wtb,
    unsigned short* __restrict__ Qb, unsigned short* __restrict__ Kb,
    unsigned short* __restrict__ Vt)
{
    const int t = threadIdx.x;
    const int w = t >> 6;                // 0:Q 1:K 2:V
    const int l = t & 63;
    const int lo = l & 15, hi = l >> 4;
    const int tok0 = blockIdx.x * 16;
    const int b  = tok0 >> 11;
    const int cb = tok0 & 2047;
    const int tile0 = blockIdx.y * 4;

    // x fragments: lane holds x[tok0+lo][kc*32 + hi*8 .. +8] as bf16
    short8 xb[4];
    const float* xrow = x + (size_t)(tok0 + lo) * IND;
#pragma unroll
    for (int kc = 0; kc < 4; ++kc) {
        const float4 a = *(const float4*)(xrow + kc * 32 + hi * 8);
        const float4 c = *(const float4*)(xrow + kc * 32 + hi * 8 + 4);
        xb[kc] = cvt8(a, c);
    }

    const unsigned short* wbase = Wtb + (size_t)(w * 128) * IND;
#pragma unroll
    for (int tile = 0; tile < 4; ++tile) {
        const int n0 = (tile0 + tile) * 16;
        short8 wf[4];
#pragma unroll
        for (int kc = 0; kc < 4; ++kc)
            wf[kc] = *(const short8*)(wbase + (size_t)(n0 + lo) * IND +
                                      kc * 32 + hi * 8);
        f4t acc = 0.f;
        if (w < 2) {
            // Yt = Wt-rows x x-rows: lane owns token=lo, cols n0+hi*4+r
#pragma unroll
            for (int kc = 0; kc < 4; ++kc) acc = MFMA32(wf[kc], xb[kc], acc);
            us4 v;
#pragma unroll
            for (int r = 0; r < 4; ++r) v[r] = f2bf(acc[r]);
            unsigned short* O = (w == 0) ? Qb : Kb;
            *(us4*)(O + (size_t)(tok0 + lo) * IND + n0 + hi * 4) = v;
        } else {
            // Y = x-rows x W-cols: lane owns d=n0+lo, tokens cb+hi*4+r
#pragma unroll
            for (int kc = 0; kc < 4; ++kc) acc = MFMA32(xb[kc], wf[kc], acc);
            us4 v;
#pragma unroll
            for (int r = 0; r < 4; ++r) v[r] = f2bf(acc[r]);
            *(us4*)(Vt + ((size_t)(b * IND) + n0 + lo) * C_ + cb + hi * 4) = v;
        }
    }
}

// ---------------------------------------------------------------------------
// K2: MFMA flash attention. Wave = 16 q x 4 heads x 512 keys (R3 shape,
// 4096 waves = 4/SIMD). R8 change: adj is the only cold-HBM stream
// (134 MB streamed once, ~900 cy latency); K/V tiles are L2-resident
// (128 KB, reused by 32 q-blocks). So: adj prefetched THREE stages ahead
// (ring of 4 f4t regs), K one stage ahead (double buffer), k-loop
// unrolled x4 so every ring slot is a named register. ~300 cy of
// compute per stage x 3-deep = ~900 cy of adj latency covered per wave,
// before counting the 4-waves/SIMD TLP. launch_bounds(256,4) keeps the
// 128-VGPR budget so the allocator holds all pipeline stages live
// (R7 lesson: default squeezed to 52 VGPR and sank the prefetch).
__global__ __launch_bounds__(256, 4) void attn_kernel(
    const unsigned short* __restrict__ Qb, const unsigned short* __restrict__ Kb,
    const unsigned short* __restrict__ Vt, const float* __restrict__ adj,
    float* __restrict__ Opart, float* __restrict__ lpart)
{
    const int t  = threadIdx.x;
    const int s  = t >> 6;               // wave id = q-subtile (0..3)
    const int l  = t & 63;
    const int lo = l & 15, hi = l >> 4;
    const int b  = blockIdx.y;
    const int kz = blockIdx.z;
    const int q0 = blockIdx.x * 64;
    const int qs = q0 + s * 16 + lo;
    const int k0base = kz * KPG;
    const int NIT = KPG / 16;            // 32

    short8 qf[4];
#pragma unroll
    for (int h = 0; h < 4; ++h)
        qf[h] = *(const short8*)(Qb + ((size_t)(b * C_) + qs) * IND + h * 32 + hi * 8);

    f4t acc[4][2];
#pragma unroll
    for (int h = 0; h < 4; ++h) { acc[h][0] = 0.f; acc[h][1] = 0.f; }
    float ls[4] = {0.f, 0.f, 0.f, 0.f};

    const float* adjrow = adj + ((size_t)(b * C_) + qs) * C_ + hi * 4;
    const unsigned short* Krow = Kb + ((size_t)(b * C_) + lo) * IND + hi * 8;
    const unsigned short* Vrow = Vt + ((size_t)(b * IND) + lo) * C_ + hi * 4;

    // All tail prefetches clamp to the last in-range stage (st = NIT-1):
    // redundant but in-bounds; their values are never consumed.
    auto loadADJ = [&](int st) -> f4t {
        const int stc = st < NIT ? st : NIT - 1;
        return *(const f4t*)(adjrow + (size_t)(k0base + stc * 16));
    };
    auto loadK = [&](int st, short8 kf[4]) {
        const int stc = st < NIT ? st : NIT - 1;
        const int k0 = k0base + stc * 16;
#pragma unroll
        for (int h = 0; h < 4; ++h)
            kf[h] = *(const short8*)(Krow + (size_t)k0 * IND + h * 32);
    };

    auto computeS = [&](const short8 kf[4], const f4t av, int st) {
        const int k0 = k0base + st * 16;
        s4t vf[8];
#pragma unroll
        for (int h = 0; h < 4; ++h) {
            vf[h * 2]     = *(const s4t*)(Vrow + (size_t)(h * 32) * C_ + k0);
            vf[h * 2 + 1] = *(const s4t*)(Vrow + (size_t)(h * 32 + 16) * C_ + k0);
        }
#pragma unroll
        for (int h = 0; h < 4; ++h) {
            f4t st4 = MFMA32(kf[h], qf[h], (f4t)0.f);
            float p[4];
#pragma unroll
            for (int r = 0; r < 4; ++r) {
                const float a = st4[r] * av[r];          // adj gate (pre-leaky)
                const float m = fmaxf(a, 0.2f * a);      // LeakyReLU(0.2)
                p[r] = exp2f(m);                         // e^s (L2E pre-folded)
                ls[h] += p[r];
            }
            const s4t pp = pack4_bf16(p[0], p[1], p[2], p[3]);
            acc[h][0] = MFMA16(pp, vf[h * 2], acc[h][0]);
            acc[h][1] = MFMA16(pp, vf[h * 2 + 1], acc[h][1]);
        }
    };

    // Software pipeline: adj ring-of-4 (3 stages ahead), K double-buffer
    // (1 stage ahead). Loop body unrolled x4 so every slot is static.
    short8 kfA[4], kfB[4];
    f4t av0, av1, av2, av3;
    av0 = loadADJ(0);
    av1 = loadADJ(1);
    av2 = loadADJ(2);
    loadK(0, kfA);
    for (int it = 0; it < NIT; it += 4) {
        av3 = loadADJ(it + 3);
        loadK(it + 1, kfB);
        computeS(kfA, av0, it);

        av0 = loadADJ(it + 4);
        loadK(it + 2, kfA);
        computeS(kfB, av1, it + 1);

        av1 = loadADJ(it + 5);
        loadK(it + 3, kfB);
        computeS(kfA, av2, it + 2);

        av2 = loadADJ(it + 6);
        loadK(it + 4, kfA);
        computeS(kfB, av3, it + 3);
    }

    // reduce l over the 4 lane-groups (k quarters) within the wave
#pragma unroll
    for (int h = 0; h < 4; ++h) {
        ls[h] += __shfl_xor(ls[h], 16, 64);
        ls[h] += __shfl_xor(ls[h], 32, 64);
    }

    const size_t BHC   = (size_t)B_ * H_ * C_;
    const size_t obase = (size_t)kz * BHC;

    // each lane writes l for head=hi, q=qs
    const float lw = (hi == 0) ? ls[0] : (hi == 1) ? ls[1] : (hi == 2) ? ls[2] : ls[3];
    lpart[obase + (size_t)(b * H_ + hi) * C_ + qs] = lw;

    // O: PV C-layout: lane owns q = q0+s*16+hi*4+r, d = h*32+dh*16+lo
#pragma unroll
    for (int h = 0; h < 4; ++h) {
        const size_t rb = obase + (size_t)(b * H_ + h) * C_ + q0 + s * 16 + hi * 4;
#pragma unroll
        for (int dh = 0; dh < 2; ++dh)
#pragma unroll
            for (int r = 0; r < 4; ++r)
                Opart[(rb + r) * D_ + dh * 16 + lo] = acc[h][dh][r];
    }
}

// ---------------------------------------------------------------------------
// K3: combine split-K partials -> AOb (bf16):  AOb = (sum O_kz)/(sum l_kz)
__global__ __launch_bounds__(256) void combine_kernel(
    const float* __restrict__ Opart, const float* __restrict__ lpart,
    unsigned short* __restrict__ AOb)
{
    const int cid = blockIdx.x * 256 + threadIdx.x;   // 0 .. 524287
    const int j   = cid & 7;                          // float4 chunk of D=32
    const int idx = cid >> 3;                         // (b*H+h)*C + q
    const int q  = idx & (C_ - 1);
    const int bh = idx >> 11;
    const int h  = bh & (H_ - 1);
    const int b  = bh >> 2;
    const size_t BHC = (size_t)B_ * H_ * C_;

    float4 acc = {0.f, 0.f, 0.f, 0.f};
    float lsum = 0.f;
#pragma unroll
    for (int kz = 0; kz < KSPLIT; ++kz) {
        const size_t base = (size_t)kz * BHC + idx;
        lsum += lpart[base];
        const float4 v = *(const float4*)(Opart + base * D_ + j * 4);
        acc.x += v.x; acc.y += v.y; acc.z += v.z; acc.w += v.w;
    }
    const float inv = 1.f / lsum;
    us4 o;
    o[0] = f2bf(acc.x * inv); o[1] = f2bf(acc.y * inv);
    o[2] = f2bf(acc.z * inv); o[3] = f2bf(acc.w * inv);
    *(us4*)(AOb + ((size_t)(b * C_) + q) * IND + h * D_ + j * 4) = o;
}

// ---------------------------------------------------------------------------
// K4: output projection via MFMA (transposed-compute -> coalesced float4
// stores with fused bias). Block = 256 = 4 waves = 4 N-quarters; 16 tokens
// per block, grid 1024 -> 4096 waves.
__global__ __launch_bounds__(256) void out_proj_kernel(
    const unsigned short* __restrict__ AOb, const unsigned short* __restrict__ Wtb,
    const float* __restrict__ bo, float* __restrict__ out)
{
    const int t  = threadIdx.x;
    const int w  = t >> 6;               // N-quarter
    const int l  = t & 63;
    const int lo = l & 15, hi = l >> 4;
    const int tok0 = blockIdx.x * 16;

    short8 af[4];
    const unsigned short* arow = AOb + (size_t)(tok0 + lo) * IND;
#pragma unroll
    for (int kc = 0; kc < 4; ++kc)
        af[kc] = *(const short8*)(arow + kc * 32 + hi * 8);

    const unsigned short* wbase = Wtb + (size_t)384 * IND;
#pragma unroll
    for (int tt = 0; tt < 2; ++tt) {
        const int n0 = w * 32 + tt * 16;
        short8 wf[4];
#pragma unroll
        for (int kc = 0; kc < 4; ++kc)
            wf[kc] = *(const short8*)(wbase + (size_t)(n0 + lo) * IND +
                                      kc * 32 + hi * 8);
        f4t acc = 0.f;
#pragma unroll
        for (int kc = 0; kc < 4; ++kc) acc = MFMA32(wf[kc], af[kc], acc);
        const f4t bv = *(const f4t*)(bo + n0 + hi * 4);
        float4 o;
        o.x = acc[0] + bv[0]; o.y = acc[1] + bv[1];
        o.z = acc[2] + bv[2]; o.w = acc[3] + bv[3];
        *(float4*)(out + (size_t)(tok0 + lo) * IND + n0 + hi * 4) = o;
    }
}

// ---------------------------------------------------------------------------
extern "C" void kernel_launch(void* const* d_in, const int* in_sizes, int n_in,
                              void* d_out, int out_size, void* d_ws, size_t ws_size,
                              hipStream_t stream) {
    const float* x   = (const float*)d_in[0];
    const float* adj = (const float*)d_in[1];
    const float* Wq  = (const float*)d_in[2];
    const float* Wk  = (const float*)d_in[3];
    const float* Wv  = (const float*)d_in[4];
    const float* Wo  = (const float*)d_in[5];
    const float* bo  = (const float*)d_in[6];
    float* out = (float*)d_out;

    // workspace (bf16 unless noted): Wtb 128KB; Qb/Kb/Vt 4.2MB each;
    // AOb 4.2MB; Opart fp32 33.6MB; lpart fp32 1MB  -> ~47.5 MB total
    unsigned short* Wtb = (unsigned short*)d_ws;
    unsigned short* Qb  = Wtb + (size_t)512 * IND;
    unsigned short* Kb  = Qb + (size_t)M_ * IND;
    unsigned short* Vt  = Kb + (size_t)M_ * IND;
    unsigned short* AOb = Vt + (size_t)M_ * IND;
    float* Opart = (float*)(AOb + (size_t)M_ * IND);
    float* lpart = Opart + (size_t)KSPLIT * B_ * H_ * C_ * D_;

    hipLaunchKernelGGL(prep_w_kernel, dim3(32), dim3(256), 0, stream,
                       Wq, Wk, Wv, Wo, Wtb);
    hipLaunchKernelGGL(qkv_proj_kernel, dim3(M_ / 16, 2), dim3(192), 0, stream,
                       x, Wtb, Qb, Kb, Vt);
    hipLaunchKernelGGL(attn_kernel, dim3(C_ / 64, B_, KSPLIT), dim3(256), 0, stream,
                       Qb, Kb, Vt, adj, Opart, lpart);
    hipLaunchKernelGGL(combine_kernel, dim3(B_ * H_ * C_ * 8 / 256), dim3(256), 0, stream,
                       Opart, lpart, AOb);
    hipLaunchKernelGGL(out_proj_kernel, dim3(M_ / 16), dim3(256), 0, stream,
                       AOb, Wtb, bo, out);
}